// Round 8
// baseline (252.500 us; speedup 1.0000x reference)
//
#include <hip/hip_runtime.h>
#include <hip/hip_bf16.h>
#include <stdint.h>

typedef unsigned short u16;
typedef __attribute__((ext_vector_type(8))) short bf16x8;
typedef __attribute__((ext_vector_type(4))) float f32x4;

#define NN 8192
#define HH 256
#define KK 100
#define BB 32
#define LL 128
#define SPLITK 8
#define KCH (NN / SPLITK)   // 1024
#define BK1 32
#define STEPS1 (KCH / BK1)  // 32
#define WCATR 1120          // padded conv-GEMM N (7 tiles x 160)

__device__ __forceinline__ u16 f2bf_rne(float x) {
  union { __hip_bfloat16 h; u16 u; } v;
  v.h = __float2bfloat16(x);
  return v.u;
}

__device__ __forceinline__ bf16x8 pack8(f32x4 a, f32x4 b) {
  bf16x8 r;
  r[0] = (short)f2bf_rne(a.x); r[1] = (short)f2bf_rne(a.y);
  r[2] = (short)f2bf_rne(a.z); r[3] = (short)f2bf_rne(a.w);
  r[4] = (short)f2bf_rne(b.x); r[5] = (short)f2bf_rne(b.y);
  r[6] = (short)f2bf_rne(b.z); r[7] = (short)f2bf_rne(b.w);
  return r;
}

// async global->LDS, 16B/lane. LDS dest wave-uniform; HW adds lane*16.
__device__ __forceinline__ void gld16(const void* g, void* l) {
  __builtin_amdgcn_global_load_lds(
      (const __attribute__((address_space(1))) unsigned int*)g,
      (__attribute__((address_space(3))) unsigned int*)l, 16, 0, 0);
}

// ---------------------------------------------------------------- embT: [256][8192] bf16 = emb^T
__global__ __launch_bounds__(256) void convert_embT(const float* __restrict__ emb,
                                                    u16* __restrict__ embT) {
  __shared__ float t[64][65];
  const int tid = threadIdx.x;
  const int k0 = blockIdx.x * 64, n0 = blockIdx.y * 64;
#pragma unroll
  for (int i = 0; i < 16; ++i) {
    int idx = i * 256 + tid;
    int r = idx >> 6, c = idx & 63;
    t[r][c] = emb[(size_t)(k0 + r) * HH + n0 + c];
  }
  __syncthreads();
#pragma unroll
  for (int i = 0; i < 16; ++i) {
    int idx = i * 256 + tid;
    int r = idx >> 6, c = idx & 63;
    embT[(size_t)(n0 + r) * NN + k0 + c] = f2bf_rne(t[c][r]);
  }
}

// ---------------------------------------------------------------- layer1 = adj @ emb (bf16 MFMA)
// T3/T4-lite: BK=32 dbuf LDS, counted vmcnt(4), raw barriers (loads in flight across barriers).
// BM=128, BN=256(all H), splitK=8, grid 512 flat (sk=wg&7 -> per-XCD embT slice), 2 blocks/CU.
__global__ __launch_bounds__(512, 4) void gemm_layer1(const float* __restrict__ adj,
                                                      const u16* __restrict__ embT,
                                                      float* __restrict__ parts) {
  __shared__ __align__(16) float As[2][128 * 32];  // 16 KB x2, swizzled (16B granule, 8-way)
  __shared__ __align__(16) u16 Bs[2][256 * 32];    // 16 KB x2, swizzled (16B granule, 4-way)
  const int tid = threadIdx.x;
  const int lane = tid & 63, wid = tid >> 6;
  const int wm = wid >> 2, wn = wid & 3;
  const int wg = blockIdx.x;
  const int sk = wg & 7;
  const int m0 = (wg >> 3) * 128;
  const int kbeg = sk * KCH;

  f32x4 acc[4][4];
  const f32x4 zf = {0.f, 0.f, 0.f, 0.f};
#pragma unroll
  for (int i = 0; i < 4; ++i)
#pragma unroll
    for (int j = 0; j < 4; ++j) acc[i][j] = zf;

  auto ISSUE = [&](int s, int buf) {
    const int ks = kbeg + s * BK1;
#pragma unroll
    for (int j = 0; j < 2; ++j) {
      int t = wid * 2 + j;
      // A: 1KB instr = 8 rows x 32 f32; lane: row=t*8+(lane>>3), 16B col=(lane&7)<<2 f32
      int rowA = t * 8 + (lane >> 3);
      int kA = ((lane & 7) << 2) ^ ((rowA & 7) << 2);
      gld16(adj + (size_t)(m0 + rowA) * NN + ks + kA, (void*)&As[buf][t * 256]);
      // B: 1KB instr = 16 rows x 32 bf16; lane: row=t*16+(lane>>2), 16B col=(lane&3)<<3 bf16
      int rowB = t * 16 + (lane >> 2);
      int kB = ((lane & 3) << 3) ^ ((rowB & 3) << 3);
      gld16(embT + (size_t)rowB * NN + ks + kB, (void*)&Bs[buf][t * 512]);
    }
  };
  auto COMPUTE = [&](int buf) {
    const int kf = (lane >> 4) << 3;  // k-offset (elements)
    bf16x8 af[4], bfr[4];
#pragma unroll
    for (int mi = 0; mi < 4; ++mi) {
      int row = wm * 64 + mi * 16 + (lane & 15);
      int g0 = (((kf >> 2) + 0) ^ (row & 7)) << 2;  // two 16B granules (order-safe)
      int g1 = (((kf >> 2) + 1) ^ (row & 7)) << 2;
      f32x4 p0 = *reinterpret_cast<const f32x4*>(&As[buf][row * 32 + g0]);
      f32x4 p1 = *reinterpret_cast<const f32x4*>(&As[buf][row * 32 + g1]);
      af[mi] = pack8(p0, p1);
    }
#pragma unroll
    for (int ni = 0; ni < 4; ++ni) {
      int row = wn * 64 + ni * 16 + (lane & 15);
      int el = kf ^ ((row & 3) << 3);
      bfr[ni] = *reinterpret_cast<const bf16x8*>(&Bs[buf][row * 32 + el]);
    }
#pragma unroll
    for (int mi = 0; mi < 4; ++mi)
#pragma unroll
      for (int ni = 0; ni < 4; ++ni)
        acc[mi][ni] = __builtin_amdgcn_mfma_f32_16x16x32_bf16(af[mi], bfr[ni], acc[mi][ni], 0, 0, 0);
  };

  ISSUE(0, 0);
  for (int s = 0; s < STEPS1; ++s) {
    if (s + 1 < STEPS1) {
      ISSUE(s + 1, (s + 1) & 1);
      asm volatile("s_waitcnt vmcnt(4)" ::: "memory");  // step-s loads done; s+1 in flight
    } else {
      asm volatile("s_waitcnt vmcnt(0)" ::: "memory");
    }
    __builtin_amdgcn_s_barrier();
    COMPUTE(s & 1);
    __builtin_amdgcn_s_barrier();  // buf reusable before next ISSUE overwrites
  }

  float* outp = parts + (size_t)sk * ((size_t)NN * HH);
  const int r0 = (lane >> 4) << 2;
  const int coln = wn * 64 + (lane & 15);
#pragma unroll
  for (int mi = 0; mi < 4; ++mi)
#pragma unroll
    for (int ni = 0; ni < 4; ++ni)
#pragma unroll
      for (int r = 0; r < 4; ++r)
        outp[(size_t)(m0 + wm * 64 + mi * 16 + r0 + r) * HH + coln + ni * 16] = acc[mi][ni][r];
}

// ---------------------------------------------------------------- gather: Q/A rows = sum of split-K parts
__global__ __launch_bounds__(256) void gather_qa(const float* __restrict__ parts,
                                                 const int* __restrict__ q_idx,
                                                 const int* __restrict__ a_idx,
                                                 float* __restrict__ Q, float* __restrict__ A) {
  const int rb = blockIdx.x;
  const bool isA = rb >= BB * LL;
  const int r = isA ? rb - BB * LL : rb;
  const int idx = (isA ? a_idx : q_idx)[r];
  const int tid = threadIdx.x;
  float s = 0.f;
#pragma unroll
  for (int p = 0; p < SPLITK; ++p)
    s += parts[(size_t)p * ((size_t)NN * HH) + (size_t)idx * HH + tid];
  (isA ? A : Q)[(size_t)r * HH + tid] = s;
}

// ---------------------------------------------------------------- score + row softmax fused
__global__ __launch_bounds__(128) void score_row(const float* __restrict__ Q,
                                                 const float* __restrict__ A,
                                                 float* __restrict__ score,
                                                 float* __restrict__ wq) {
  __shared__ float qs[HH];
  __shared__ float red[4];
  const int bl = blockIdx.x;
  const int b = bl >> 7;
  const int tid = threadIdx.x;
  const int wv = tid >> 6, lane = tid & 63;
  qs[tid] = Q[(size_t)bl * HH + tid];
  qs[tid + 128] = Q[(size_t)bl * HH + tid + 128];
  __syncthreads();
  const float4* a4 = reinterpret_cast<const float4*>(A + ((size_t)b * LL + tid) * HH);
  const float4* q4 = reinterpret_cast<const float4*>(qs);
  float acc = 0.f;
#pragma unroll 8
  for (int h = 0; h < HH / 4; ++h) {
    float4 av = a4[h], qv = q4[h];
    acc += av.x * qv.x + av.y * qv.y + av.z * qv.z + av.w * qv.w;
  }
  float mx = acc;
#pragma unroll
  for (int off = 32; off; off >>= 1) mx = fmaxf(mx, __shfl_xor(mx, off));
  if (lane == 0) red[wv] = mx;
  __syncthreads();
  mx = fmaxf(red[0], red[1]);
  float e = expf(acc - mx);
  float sm = e;
#pragma unroll
  for (int off = 32; off; off >>= 1) sm += __shfl_xor(sm, off);
  if (lane == 0) red[2 + wv] = sm;
  __syncthreads();
  sm = red[2] + red[3];
  score[(size_t)bl * LL + tid] = acc;
  wq[(size_t)bl * LL + tid] = e / sm;
}

// ---------------------------------------------------------------- col softmax via LDS-staged per-b tile
// block = b (32 blocks, 256 thr). sc[128][132] pad -> conflict-free column walks.
__global__ __launch_bounds__(256) void softmax_colB(const float* __restrict__ score,
                                                    float* __restrict__ waT) {
  __shared__ float sc[128 * 132];
  const int b = blockIdx.x;
  const int tid = threadIdx.x;
  const float4* src = reinterpret_cast<const float4*>(score + (size_t)b * LL * LL);
#pragma unroll
  for (int i = 0; i < 16; ++i) {
    int f4i = i * 256 + tid;          // 4096 float4s
    int l = f4i >> 5, m4 = f4i & 31;
    *reinterpret_cast<float4*>(&sc[l * 132 + m4 * 4]) = src[f4i];
  }
  __syncthreads();
  if (tid < 128) {
    const int m = tid;
    float mx = -3.4e38f;
    for (int l = 0; l < 128; ++l) mx = fmaxf(mx, sc[l * 132 + m]);
    float sum = 0.f;
    for (int l = 0; l < 128; ++l) {
      float e = expf(sc[l * 132 + m] - mx);
      sc[l * 132 + m] = e;
      sum += e;
    }
    float inv = 1.f / sum;
    for (int l = 0; l < 128; ++l) sc[l * 132 + m] *= inv;
  }
  __syncthreads();
  float* dst = waT + (size_t)b * LL * LL;
#pragma unroll
  for (int i = 0; i < 64; ++i) {
    int idx = i * 256 + tid;           // out flat = m*128 + l
    int m = idx >> 7, l = idx & 127;
    dst[idx] = sc[l * 132 + m];
  }
}

// ---------------------------------------------------------------- align+encode: EQ/EA + match features -> Tbf
__global__ __launch_bounds__(1024) void align_encode(const float* __restrict__ wq,
                                                     const float* __restrict__ waT,
                                                     const float* __restrict__ Q,
                                                     const float* __restrict__ A,
                                                     u16* __restrict__ Tbf) {
  __shared__ float wl[128 * 128];
  __shared__ float sl[128 * 64];
  const int bid = blockIdx.x;
  const int side = bid >> 7;
  const int b = (bid >> 2) & 31;
  const int h0 = (bid & 3) * 64;
  const int tid = threadIdx.x;
  const int lt = tid >> 6, hx = tid & 63;

  const float* wsrc = (side ? waT : wq) + (size_t)b * (LL * LL);
  const float* ssrc = (side ? Q : A) + (size_t)b * (LL * HH) + h0;
  const float* msrc = (side ? A : Q) + (size_t)b * (LL * HH) + h0;

#pragma unroll
  for (int i = 0; i < 16; ++i) {
    int idx = i * 1024 + tid;
    wl[idx] = wsrc[idx];
  }
#pragma unroll
  for (int i = 0; i < 8; ++i) {
    int idx = i * 1024 + tid;
    int r = idx >> 6, c = idx & 63;
    sl[idx] = ssrc[(size_t)r * HH + c];
  }
  __syncthreads();

  float accv[8];
#pragma unroll
  for (int ii = 0; ii < 8; ++ii) accv[ii] = 0.f;

  for (int j4 = 0; j4 < 128; j4 += 4) {
    float s0 = sl[(j4 + 0) * 64 + hx];
    float s1 = sl[(j4 + 1) * 64 + hx];
    float s2 = sl[(j4 + 2) * 64 + hx];
    float s3 = sl[(j4 + 3) * 64 + hx];
#pragma unroll
    for (int ii = 0; ii < 8; ++ii) {
      float4 wv = *reinterpret_cast<const float4*>(&wl[(lt + 16 * ii) * 128 + j4]);
      accv[ii] += wv.x * s0 + wv.y * s1 + wv.z * s2 + wv.w * s3;
    }
  }

  u16* outp = Tbf + (size_t)(side * 4096 + b * 128) * 512 + h0;
#pragma unroll
  for (int ii = 0; ii < 8; ++ii) {
    int i = lt + 16 * ii;
    float mv = msrc[(size_t)i * HH + hx];
    float e = accv[ii];
    float d = mv - e;
    outp[(size_t)i * 512 + hx] = f2bf_rne(d * d);
    outp[(size_t)i * 512 + 256 + hx] = f2bf_rne(mv * e);
  }
}

// ---------------------------------------------------------------- Wcat bf16 [1120][512]
__global__ __launch_bounds__(256) void prep_wcat(const float* __restrict__ w0,
                                                 const float* __restrict__ w1,
                                                 const float* __restrict__ w2,
                                                 const float* __restrict__ w3,
                                                 u16* __restrict__ Wcat) {
  const int kr = blockIdx.x;
  const int tid = threadIdx.x;
  u16* out = Wcat + (size_t)kr * 512;
  if (kr >= KK * 10) {
    out[tid] = 0;
    out[tid + 256] = 0;
    return;
  }
  const int k = kr / 10, s = kr % 10;
  const float* w;
  int r, fs;
  if (s < 1)      { w = w0; r = s;     fs = 1; }
  else if (s < 3) { w = w1; r = s - 1; fs = 2; }
  else if (s < 6) { w = w2; r = s - 3; fs = 3; }
  else            { w = w3; r = s - 6; fs = 4; }
  const float* src = w + ((size_t)k * fs + r) * 522 + 5;
  out[tid] = f2bf_rne(src[tid]);
  out[tid + 256] = f2bf_rne(src[tid + 256]);
}

// ---------------------------------------------------------------- fused conv GEMM + shift-sum/relu/maxpool -> re
// BM=128 (= one (sel,b)), BN=160 (16 k-groups), K=512. grid = 64 pairs x 7 ntiles = 448.
// 8 waves as 4M x 2N; acc[2][5]. Epilogue via Dt[128][162] LDS.
__global__ __launch_bounds__(512, 4) void gemm_conv_fused(const u16* __restrict__ Tbf,
                                                          const u16* __restrict__ Wcat,
                                                          const float* __restrict__ b0,
                                                          const float* __restrict__ b1,
                                                          const float* __restrict__ b2,
                                                          const float* __restrict__ b3,
                                                          float* __restrict__ re) {
  __shared__ __align__(16) u16 AsC[128 * 64];    // 16 KB
  __shared__ __align__(16) u16 BsC[160 * 64];    // 20 KB
  __shared__ float Dt[128 * 162];                // 83 KB
  const int tid = threadIdx.x;
  const int lane = tid & 63, wid = tid >> 6;
  const int wm = wid >> 1, wn = wid & 1;
  const int bx = blockIdx.x;
  const int pair = bx / 7, nt = bx % 7;
  const int sel = pair >> 5, b = pair & 31;
  const int m0 = pair * 128;
  const int n0 = nt * 160;

  f32x4 acc[2][5];
  const f32x4 zf = {0.f, 0.f, 0.f, 0.f};
#pragma unroll
  for (int i = 0; i < 2; ++i)
#pragma unroll
    for (int j = 0; j < 5; ++j) acc[i][j] = zf;

  for (int s = 0; s < 8; ++s) {
    const int ks = s * 64;
#pragma unroll
    for (int j = 0; j < 2; ++j) {
      int t = wid * 2 + j;
      int rowA = t * 8 + (lane >> 3);
      int kA = ((lane & 7) << 3) ^ ((rowA & 7) << 3);
      gld16(Tbf + (size_t)(m0 + rowA) * 512 + ks + kA, (void*)&AsC[t * 512]);
    }
    for (int t = wid; t < 20; t += 8) {
      int rowB = t * 8 + (lane >> 3);
      int kB = ((lane & 7) << 3) ^ ((rowB & 7) << 3);
      gld16(Wcat + (size_t)(n0 + rowB) * 512 + ks + kB, (void*)&BsC[t * 512]);
    }
    __syncthreads();
#pragma unroll
    for (int kk = 0; kk < 64; kk += 32) {
      const int k8 = kk + ((lane >> 4) << 3);
      bf16x8 af[2], bfr[5];
#pragma unroll
      for (int mi = 0; mi < 2; ++mi) {
        int row = wm * 32 + mi * 16 + (lane & 15);
        int el = ((k8 >> 3) ^ (row & 7)) << 3;
        af[mi] = *reinterpret_cast<const bf16x8*>(&AsC[row * 64 + el]);
      }
#pragma unroll
      for (int ni = 0; ni < 5; ++ni) {
        int row = wn * 80 + ni * 16 + (lane & 15);
        int el = ((k8 >> 3) ^ (row & 7)) << 3;
        bfr[ni] = *reinterpret_cast<const bf16x8*>(&BsC[row * 64 + el]);
      }
#pragma unroll
      for (int mi = 0; mi < 2; ++mi)
#pragma unroll
        for (int ni = 0; ni < 5; ++ni)
          acc[mi][ni] = __builtin_amdgcn_mfma_f32_16x16x32_bf16(af[mi], bfr[ni], acc[mi][ni], 0, 0, 0);
    }
    __syncthreads();
  }

  // acc -> Dt
  const int r0 = (lane >> 4) << 2;
#pragma unroll
  for (int mi = 0; mi < 2; ++mi)
#pragma unroll
    for (int ni = 0; ni < 5; ++ni) {
      int col = wn * 80 + ni * 16 + (lane & 15);
#pragma unroll
      for (int r = 0; r < 4; ++r)
        Dt[(wm * 32 + mi * 16 + r0 + r) * 162 + col] = acc[mi][ni][r];
    }
  __syncthreads();

  // epilogue: 64 outputs (16 k x 4 f), 8 per wave
  const int offt[4] = {0, 1, 3, 6};
  const int fst[4] = {1, 2, 3, 4};
#pragma unroll
  for (int oi = 0; oi < 8; ++oi) {
    const int o = wid * 8 + oi;
    const int kl = o >> 2, f = o & 3;
    const int kglob = nt * 16 + kl;
    if (kglob >= KK) continue;
    const int fs = fst[f], off = offt[f];
    const float bias = (f == 0 ? b0 : f == 1 ? b1 : f == 2 ? b2 : b3)[kglob];
    const int col = kl * 10 + off;
    const int outh = 139 - fs;
    float best = 0.f;
    for (int i = lane; i < outh; i += 64) {
      float s = bias;
#pragma unroll 4
      for (int r = 0; r < 4; ++r) {
        if (r < fs) {
          int j = i + r - 5;
          if (j >= 0 && j < LL) s += Dt[j * 162 + col + r];
        }
      }
      best = fmaxf(best, s);
    }
    best = fmaxf(best, 0.f);
#pragma unroll
    for (int d = 32; d; d >>= 1) best = fmaxf(best, __shfl_xor(best, d));
    if (lane == 0) re[(size_t)b * 800 + sel * 400 + f * 100 + kglob] = best;
  }
}

// ---------------------------------------------------------------- dense + log_softmax -> out[32][2]
__global__ __launch_bounds__(64) void dense_logsm(const float* __restrict__ re,
                                                  const float* __restrict__ dw,
                                                  const float* __restrict__ db,
                                                  float* __restrict__ out) {
  const int b = blockIdx.x;
  const int lane = threadIdx.x;
  const float* r = re + (size_t)b * 800;
  float a0 = 0.f, a1 = 0.f;
  for (int j = lane; j < 800; j += 64) {
    float rv = r[j];
    a0 += rv * dw[j * 2];
    a1 += rv * dw[j * 2 + 1];
  }
#pragma unroll
  for (int d = 32; d; d >>= 1) {
    a0 += __shfl_xor(a0, d);
    a1 += __shfl_xor(a1, d);
  }
  if (lane == 0) {
    a0 += db[0];
    a1 += db[1];
    float mx = fmaxf(a0, a1);
    float lse = mx + logf(expf(a0 - mx) + expf(a1 - mx));
    out[b * 2] = a0 - lse;
    out[b * 2 + 1] = a1 - lse;
  }
}

// ---------------------------------------------------------------- workspace layout (bytes)
static const size_t OFF_PARTS = 0;                           // 8 x 8 MB = 67,108,864
static const size_t OFF_Q     = 67108864;
static const size_t OFF_A     = OFF_Q + 4194304;
static const size_t OFF_SCORE = OFF_A + 4194304;
static const size_t OFF_WQ    = OFF_SCORE + 2097152;
static const size_t OFF_WAT   = OFF_WQ + 2097152;
static const size_t OFF_RE    = OFF_WAT + 2097152;
static const size_t OFF_TBF   = OFF_RE + 102400;             // bf16 [8192][512]
static const size_t OFF_WCAT  = OFF_TBF + 8388608;           // bf16 [1120][512]
static const size_t OFF_EMBT  = OFF_WCAT + 1146880;          // bf16 [256][8192]

extern "C" void kernel_launch(void* const* d_in, const int* in_sizes, int n_in,
                              void* d_out, int out_size, void* d_ws, size_t ws_size,
                              hipStream_t stream) {
  (void)in_sizes; (void)n_in; (void)out_size; (void)ws_size;
  const float* adj  = (const float*)d_in[0];
  const float* emb  = (const float*)d_in[1];
  const int* q_idx  = (const int*)d_in[2];
  const int* a_idx  = (const int*)d_in[3];
  const float* cw0 = (const float*)d_in[4];
  const float* cb0 = (const float*)d_in[5];
  const float* cw1 = (const float*)d_in[6];
  const float* cb1 = (const float*)d_in[7];
  const float* cw2 = (const float*)d_in[8];
  const float* cb2 = (const float*)d_in[9];
  const float* cw3 = (const float*)d_in[10];
  const float* cb3 = (const float*)d_in[11];
  const float* dw = (const float*)d_in[12];
  const float* db = (const float*)d_in[13];
  float* out = (float*)d_out;

  char* ws = (char*)d_ws;
  float* parts = (float*)(ws + OFF_PARTS);
  float* Q     = (float*)(ws + OFF_Q);
  float* Abuf  = (float*)(ws + OFF_A);
  float* score = (float*)(ws + OFF_SCORE);
  float* wq    = (float*)(ws + OFF_WQ);
  float* waT   = (float*)(ws + OFF_WAT);
  float* re    = (float*)(ws + OFF_RE);
  u16* Tbf     = (u16*)(ws + OFF_TBF);
  u16* Wcat    = (u16*)(ws + OFF_WCAT);
  u16* embT    = (u16*)(ws + OFF_EMBT);

  convert_embT<<<dim3(128, 4), 256, 0, stream>>>(emb, embT);
  prep_wcat<<<WCATR, 256, 0, stream>>>(cw0, cw1, cw2, cw3, Wcat);
  gemm_layer1<<<64 * SPLITK, 512, 0, stream>>>(adj, embT, parts);
  gather_qa<<<2 * BB * LL, 256, 0, stream>>>(parts, q_idx, a_idx, Q, Abuf);
  score_row<<<BB * LL, 128, 0, stream>>>(Q, Abuf, score, wq);
  softmax_colB<<<BB, 256, 0, stream>>>(score, waT);
  align_encode<<<256, 1024, 0, stream>>>(wq, waT, Q, Abuf, Tbf);
  gemm_conv_fused<<<448, 512, 0, stream>>>(Tbf, Wcat, cb0, cb1, cb2, cb3, re);
  dense_logsm<<<BB, 64, 0, stream>>>(re, dw, db, out);
}